// Round 11
// baseline (227.813 us; speedup 1.0000x reference)
//
#include <hip/hip_runtime.h>
#include <hip/hip_bf16.h>

#define IN_F   1024
#define OUT_F  1024
#define NCH    9
#define KDIM   9216               // 9 channels * 1024 features, channel-major: k = c*1024 + f
#define BATCH  8192

// ---- GEMM: 256x256 tile, BK=32, 8 waves (2M x 4N), A-only 4-slot LDS ring,
// ---- B pre-swizzled to fragment order in global (reg double-buffered), K-split x2
#define BM 256
#define BN 256
#define BK 32
#define KHALF 4608
#define NTK (KHALF / BK)          // 144 K-tiles per half
#define SLOTA 8192                // u16 per ring slot: A only (16 KiB)
#define KCH  288                  // total k-chunks (KDIM/32)

typedef __attribute__((ext_vector_type(4)))  float  f32x4;
typedef __attribute__((ext_vector_type(8)))  __bf16 bf16x8;

typedef __attribute__((address_space(3))) unsigned short       lds_u16;
typedef const __attribute__((address_space(1))) unsigned short glb_u16;

__device__ inline unsigned short f2bf(float f) {
    union { float f; unsigned int u; } v; v.f = f;
    unsigned int u = v.u;
    unsigned int r = (u + 0x7FFFu + ((u >> 16) & 1u)) >> 16;   // RNE
    return (unsigned short)r;
}

// ---------------------------------------------------------------------------
// Kernel 1 (merged prep): blocks [0, 4096) = activations, [4096, 8192) = weights.
//
// act: A[r][c*1024 + f] channel-major, 8 features/thread, 16B stores.
// wgt: W stored in MFMA-FRAGMENT order: u16 index
//      ((nb*KCH + kc)<<9) + lane*8 + j
//      where nb = o>>4, kc = c*32 + (f>>5), lane = (o&15) + (((f>>3)&3)<<4),
//      j = f&7  — so a wave's 64 lanes read one contiguous 1KB block per
//      fragment (fully coalesced), lane l holding W[nb*16+(l&15)][kc*32+(l>>4)*8+j].
// ---------------------------------------------------------------------------
__global__ void prep_kernel(const float* __restrict__ x,
                            const float* __restrict__ bw,
                            const float* __restrict__ sw,
                            const float* __restrict__ sc,
                            unsigned short* __restrict__ A,
                            unsigned short* __restrict__ Wf) {
    const int bid = blockIdx.x;
    if (bid < 4096) {
        // ---------------- activations ----------------
        int idx = bid * 256 + threadIdx.x;               // r*128 + f8
        const float4* xp = (const float4*)(x + (size_t)idx * 8);
        float4 x0 = xp[0], x1 = xp[1];
        float xs[8] = {x0.x, x0.y, x0.z, x0.w, x1.x, x1.y, x1.z, x1.w};

        unsigned short vals[8][9];
#pragma unroll
        for (int e = 0; e < 8; ++e) {
            float v  = xs[e];
            float s  = v / (1.0f + __expf(-v));          // silu
            float t  = (v + 2.2f) * 2.5f;                // (x - g0)/h
            float jf = floorf(t);
            int   j  = (int)jf;
            float u  = t - jf;
            float u2 = u * u, u3 = u2 * u;
            float p0 = u3 * (1.0f / 6.0f);
            float p1 = (-3.0f * u3 + 3.0f * u2 + 3.0f * u + 1.0f) * (1.0f / 6.0f);
            float p2 = (3.0f * u3 - 6.0f * u2 + 4.0f) * (1.0f / 6.0f);
            float om = 1.0f - u;
            float p3 = om * om * om * (1.0f / 6.0f);
            bool valid = (v >= -2.2f) && (v < 2.2f);
#pragma unroll
            for (int c = 0; c < 8; ++c) {
                int p = j - c;
                float bv = 0.0f;
                if (valid)
                    bv = (p == 0) ? p0 : (p == 1) ? p1 : (p == 2) ? p2 : (p == 3) ? p3 : 0.0f;
                vals[e][c] = f2bf(bv);
            }
            vals[e][8] = f2bf(s);
        }

        int r = idx >> 7, f8 = idx & 127;
        unsigned short* base = A + (size_t)r * KDIM + f8 * 8;
#pragma unroll
        for (int c = 0; c < 9; ++c) {
            uint4 pk;
            pk.x = (unsigned int)vals[0][c] | ((unsigned int)vals[1][c] << 16);
            pk.y = (unsigned int)vals[2][c] | ((unsigned int)vals[3][c] << 16);
            pk.z = (unsigned int)vals[4][c] | ((unsigned int)vals[5][c] << 16);
            pk.w = (unsigned int)vals[6][c] | ((unsigned int)vals[7][c] << 16);
            *(uint4*)(base + (size_t)c * 1024) = pk;
        }
    } else {
        // ---------------- weights (fragment-order) ----------------
        int idx = (bid - 4096) * 256 + threadIdx.x;      // o*1024 + f
        int o = idx >> 10, f = idx & 1023;
        float scale = sc[idx];
        const float4* swp = (const float4*)(sw + (size_t)idx * 8);
        float4 w0 = swp[0], w1 = swp[1];
        float wv[9] = {w0.x * scale, w0.y * scale, w0.z * scale, w0.w * scale,
                       w1.x * scale, w1.y * scale, w1.z * scale, w1.w * scale,
                       bw[idx]};
        const int nb   = o >> 4;
        const int lane = (o & 15) + (((f >> 3) & 3) << 4);
        const int jj   = f & 7;
        const int kcf  = f >> 5;
#pragma unroll
        for (int c = 0; c < 9; ++c) {
            size_t ui = (((size_t)nb * KCH + (c * 32 + kcf)) << 9) + lane * 8 + jj;
            Wf[ui] = f2bf(wv[c]);
        }
    }
}

// ---------------------------------------------------------------------------
// Kernel 2: K-split GEMM, 16x16x32 MFMA (r7-proven schedule), A-only LDS ring.
// - A: 4-slot ring (64 KiB), stage t+3, swizzle cl = (chunk ^ ((row>>1)&3))
//   (r6/r7-measured conflict-free), ONE barrier per tile.
// - B: fragment-order global loads (1KB/wave coalesced, L2-resident),
//   register double-buffered one tile ahead (bA/bB sets, static names).
// - Boundary wait counted: in-flight = A(t+2)2 + A(t+3)2 + B(t+1)4 = vmcnt(8).
// C/D 16x16: col=lane&15, row=(lane>>4)*4+r  [m89/m91].
// ---------------------------------------------------------------------------
#define DECLS(q) \
    const int ci##q = (q) * 512 + tid; \
    const int lo##q = ci##q << 3; \
    const int rr##q = ci##q >> 2; \
    const int cl##q = (((ci##q & 3) ^ ((rr##q >> 1) & 3)) << 3); \
    const unsigned short* srcA##q = Ap + (size_t)(m0 + rr##q) * KDIM + kbase + cl##q;

#define STAGE_A(q, ns) do { \
    __builtin_amdgcn_global_load_lds((glb_u16*)srcA##q, (lds_u16*)(ns) + lo##q, 16, 0, 0); \
    srcA##q += BK; } while (0)

#define RDA(mi) (*(const bf16x8*)&sA[(rowa + (mi) * 16) * BK + koff])

#define LDB(ni, tt) (*(const bf16x8*)&Wf[((((size_t)(nbB + (ni))) * KCH + kcb + (tt)) << 9) + lsh])

#define MM4(av, mi, B0, B1, B2, B3) \
    acc[mi][0] = __builtin_amdgcn_mfma_f32_16x16x32_bf16(av, B0, acc[mi][0], 0, 0, 0); \
    acc[mi][1] = __builtin_amdgcn_mfma_f32_16x16x32_bf16(av, B1, acc[mi][1], 0, 0, 0); \
    acc[mi][2] = __builtin_amdgcn_mfma_f32_16x16x32_bf16(av, B2, acc[mi][2], 0, 0, 0); \
    acc[mi][3] = __builtin_amdgcn_mfma_f32_16x16x32_bf16(av, B3, acc[mi][3], 0, 0, 0);

#define BODY(t, C0, C1, C2, C3, N0, N1, N2, N3) do { \
    unsigned short* ns = lds + (((t) + 3) & 3) * SLOTA; \
    if ((t) + 3 < NTK) { STAGE_A(0, ns); STAGE_A(1, ns); } \
    if ((t) + 1 < NTK) { N0 = LDB(0, (t) + 1); N1 = LDB(1, (t) + 1); \
                         N2 = LDB(2, (t) + 1); N3 = LDB(3, (t) + 1); } \
    const unsigned short* sA = lds + ((t) & 3) * SLOTA; \
    __builtin_amdgcn_s_setprio(1); \
    { bf16x8 a0 = RDA(0); MM4(a0, 0, C0, C1, C2, C3) } \
    { bf16x8 a1 = RDA(1); MM4(a1, 1, C0, C1, C2, C3) } \
    { bf16x8 a2 = RDA(2); MM4(a2, 2, C0, C1, C2, C3) } \
    { bf16x8 a3 = RDA(3); MM4(a3, 3, C0, C1, C2, C3) } \
    { bf16x8 a4 = RDA(4); MM4(a4, 4, C0, C1, C2, C3) } \
    { bf16x8 a5 = RDA(5); MM4(a5, 5, C0, C1, C2, C3) } \
    { bf16x8 a6 = RDA(6); MM4(a6, 6, C0, C1, C2, C3) } \
    { bf16x8 a7 = RDA(7); MM4(a7, 7, C0, C1, C2, C3) } \
    __builtin_amdgcn_s_setprio(0); \
    if ((t) <= NTK - 4)      asm volatile("s_waitcnt vmcnt(8)" ::: "memory"); \
    else if ((t) == NTK - 3) asm volatile("s_waitcnt vmcnt(6)" ::: "memory"); \
    else if ((t) == NTK - 2) asm volatile("s_waitcnt vmcnt(4)" ::: "memory"); \
    else                     asm volatile("s_waitcnt vmcnt(0)" ::: "memory"); \
    __builtin_amdgcn_s_barrier(); \
} while (0)

__global__ __launch_bounds__(512, 2) void gemm_bg(
    const unsigned short* __restrict__ Ap,
    const unsigned short* __restrict__ Wf,
    float* __restrict__ C, float* __restrict__ P, int mode) {
    __shared__ unsigned short lds[4 * SLOTA];            // 64 KiB A-ring

    const int tid  = threadIdx.x;
    const int wave = tid >> 6;
    const int lane = tid & 63;
    const int lm16 = lane & 15;
    const int lhi  = lane >> 4;
    const int koff = ((lhi ^ ((lm16 >> 1) & 3)) << 3);   // r7 conflict-free read
    const int lsh  = lane << 3;                          // B-frag lane offset (u16)

    // bid -> (kb, m, n): XCD x = bid&7 fixed (kb = bit2, mgroup = bits 0-1);
    // within an XCD: 8 m-panels x 4 n -> A,B panels L2-resident per XCD.
    const int bid  = blockIdx.x;
    const int mg   = bid & 3;
    const int kb   = (bid >> 2) & 1;
    const int j    = bid >> 3;
    const int m0   = (mg * 8 + (j >> 2)) * BM;
    const int n0   = (j & 3) * BN;
    const int kbase = kb * KHALF;

    const int wr = wave >> 2;                            // 0..1 (M)
    const int wc = wave & 3;                             // 0..3 (N)
    const int rowa = wr * 128 + lm16;
    const int nbB  = (n0 >> 4) + wc * 4;                 // B fragment n-block
    const int kcb  = kb * NTK;                           // B k-chunk base

    f32x4 acc[8][4];
#pragma unroll
    for (int i = 0; i < 8; ++i)
#pragma unroll
        for (int jn = 0; jn < 4; ++jn) acc[i][jn] = (f32x4)(0.0f);

    DECLS(0) DECLS(1)

    bf16x8 bA0, bA1, bA2, bA3, bB0, bB1, bB2, bB3;

    // prologue: A tiles 0,1,2 -> slots 0,1,2; B tile 0 -> bA set
    {
        unsigned short* ns = lds;
        STAGE_A(0, ns); STAGE_A(1, ns);
    }
    bA0 = LDB(0, 0); bA1 = LDB(1, 0); bA2 = LDB(2, 0); bA3 = LDB(3, 0);
    {
        unsigned short* ns = lds + SLOTA;
        STAGE_A(0, ns); STAGE_A(1, ns);
    }
    {
        unsigned short* ns = lds + 2 * SLOTA;
        STAGE_A(0, ns); STAGE_A(1, ns);
    }
    asm volatile("s_waitcnt vmcnt(8)" ::: "memory");     // A0 + B0 landed
    __builtin_amdgcn_s_barrier();

#pragma unroll 2
    for (int t = 0; t < NTK; t += 2) {
        BODY(t,     bA0, bA1, bA2, bA3, bB0, bB1, bB2, bB3);
        BODY(t + 1, bB0, bB1, bB2, bB3, bA0, bA1, bA2, bA3);
    }

    // epilogue: C/D layout col = lane&15, row = (lane>>4)*4 + r
    const int orow = m0 + wr * 128 + (lhi << 2);
    const int ocol = n0 + wc * 64 + lm16;
    if (mode) {
#pragma unroll
        for (int mi = 0; mi < 8; ++mi)
#pragma unroll
            for (int ni = 0; ni < 4; ++ni)
#pragma unroll
                for (int r = 0; r < 4; ++r)
                    atomicAdd(&C[(size_t)(orow + mi * 16 + r) * OUT_F + (ocol + ni * 16)], acc[mi][ni][r]);
    } else {
        float* dst = kb ? P : C;
#pragma unroll
        for (int mi = 0; mi < 8; ++mi)
#pragma unroll
            for (int ni = 0; ni < 4; ++ni)
#pragma unroll
                for (int r = 0; r < 4; ++r)
                    dst[(size_t)(orow + mi * 16 + r) * OUT_F + (ocol + ni * 16)] = acc[mi][ni][r];
    }
}

// ---------------------------------------------------------------------------
// Kernel 3: C += P (K-split reduction), float4.
// ---------------------------------------------------------------------------
__global__ void add_kernel(float* __restrict__ C, const float* __restrict__ P) {
    int i = blockIdx.x * blockDim.x + threadIdx.x;
    if (i >= BATCH * OUT_F / 4) return;
    f32x4* c4 = (f32x4*)C;
    const f32x4* p4 = (const f32x4*)P;
    c4[i] = c4[i] + p4[i];
}

// ---------------------------------------------------------------------------
extern "C" void kernel_launch(void* const* d_in, const int* in_sizes, int n_in,
                              void* d_out, int out_size, void* d_ws, size_t ws_size,
                              hipStream_t stream) {
    const float* x             = (const float*)d_in[0];
    const float* base_weight   = (const float*)d_in[1];
    const float* spline_weight = (const float*)d_in[2];
    const float* spline_scaler = (const float*)d_in[3];
    float* out = (float*)d_out;

    const size_t wbytes = (size_t)OUT_F * KDIM * 2;      // 18.9 MB
    const size_t abytes = (size_t)BATCH * KDIM * 2;      // 151 MB
    const size_t pbytes = (size_t)BATCH * OUT_F * 4;     // 33.5 MB
    unsigned short* Wf   = (unsigned short*)d_ws;
    unsigned short* Abuf = (unsigned short*)((char*)d_ws + wbytes);
    float*          P    = (float*)((char*)d_ws + wbytes + abytes);

    const int mode = (ws_size >= wbytes + abytes + pbytes) ? 0 : 1;
    if (mode == 1)
        (void)hipMemsetAsync(d_out, 0, pbytes, stream);  // atomic fallback needs zeroed C

    prep_kernel<<<8192, 256, 0, stream>>>(x, base_weight, spline_weight,
                                          spline_scaler, Abuf, Wf);

    gemm_bg<<<256, 512, 0, stream>>>(Abuf, Wf, out, P, mode);

    if (mode == 0)
        add_kernel<<<(BATCH * OUT_F / 4 + 255) / 256, 256, 0, stream>>>(out, P);
}

// Round 12
// 195.138 us; speedup vs baseline: 1.1674x; 1.1674x over previous
//
#include <hip/hip_runtime.h>
#include <hip/hip_bf16.h>

#define IN_F   1024
#define OUT_F  1024
#define NCH    9
#define KDIM   9216               // 9 channels * 1024 features, channel-major
#define BATCH  8192

// ---- GEMM: 256x256 tile, BK=64, 8 waves (2M x 4N), m201 8-phase, K-split x2 ----
#define BM 256
#define BN 256
#define BK 64
#define KHALF 4608
#define NTK (KHALF / BK)          // 72 K-tiles per half
#define NT2 (NTK / 2)             // 36 iterations of 2 K-tiles

typedef __attribute__((ext_vector_type(4)))  float  f32x4;
typedef __attribute__((ext_vector_type(8)))  __bf16 bf16x8;

typedef __attribute__((address_space(3))) unsigned short       lds_u16;
typedef const __attribute__((address_space(1))) unsigned short glb_u16;

__device__ inline unsigned short f2bf(float f) {
    union { float f; unsigned int u; } v; v.f = f;
    unsigned int u = v.u;
    unsigned int r = (u + 0x7FFFu + ((u >> 16) & 1u)) >> 16;   // RNE
    return (unsigned short)r;
}

// ---------------------------------------------------------------------------
// Kernel 1 (merged prep): blocks [0,4096) activations, [4096,8192) weights.
// Both outputs channel-major: X[row][c*1024 + f].
// ---------------------------------------------------------------------------
__global__ void prep_kernel(const float* __restrict__ x,
                            const float* __restrict__ bw,
                            const float* __restrict__ sw,
                            const float* __restrict__ sc,
                            unsigned short* __restrict__ A,
                            unsigned short* __restrict__ W) {
    const int bid = blockIdx.x;
    if (bid < 4096) {
        int idx = bid * 256 + threadIdx.x;               // r*128 + f8
        const float4* xp = (const float4*)(x + (size_t)idx * 8);
        float4 x0 = xp[0], x1 = xp[1];
        float xs[8] = {x0.x, x0.y, x0.z, x0.w, x1.x, x1.y, x1.z, x1.w};

        unsigned short vals[8][9];
#pragma unroll
        for (int e = 0; e < 8; ++e) {
            float v  = xs[e];
            float s  = v / (1.0f + __expf(-v));          // silu
            float t  = (v + 2.2f) * 2.5f;                // (x - g0)/h
            float jf = floorf(t);
            int   j  = (int)jf;
            float u  = t - jf;
            float u2 = u * u, u3 = u2 * u;
            float p0 = u3 * (1.0f / 6.0f);
            float p1 = (-3.0f * u3 + 3.0f * u2 + 3.0f * u + 1.0f) * (1.0f / 6.0f);
            float p2 = (3.0f * u3 - 6.0f * u2 + 4.0f) * (1.0f / 6.0f);
            float om = 1.0f - u;
            float p3 = om * om * om * (1.0f / 6.0f);
            bool valid = (v >= -2.2f) && (v < 2.2f);
#pragma unroll
            for (int c = 0; c < 8; ++c) {
                int p = j - c;
                float bv = 0.0f;
                if (valid)
                    bv = (p == 0) ? p0 : (p == 1) ? p1 : (p == 2) ? p2 : (p == 3) ? p3 : 0.0f;
                vals[e][c] = f2bf(bv);
            }
            vals[e][8] = f2bf(s);
        }

        int r = idx >> 7, f8 = idx & 127;
        unsigned short* base = A + (size_t)r * KDIM + f8 * 8;
#pragma unroll
        for (int c = 0; c < 9; ++c) {
            uint4 pk;
            pk.x = (unsigned int)vals[0][c] | ((unsigned int)vals[1][c] << 16);
            pk.y = (unsigned int)vals[2][c] | ((unsigned int)vals[3][c] << 16);
            pk.z = (unsigned int)vals[4][c] | ((unsigned int)vals[5][c] << 16);
            pk.w = (unsigned int)vals[6][c] | ((unsigned int)vals[7][c] << 16);
            *(uint4*)(base + (size_t)c * 1024) = pk;
        }
    } else {
        int idx = (bid - 4096) * 256 + threadIdx.x;      // o*1024 + f
        int o = idx >> 10, f = idx & 1023;
        float scale = sc[idx];
        const float4* swp = (const float4*)(sw + (size_t)idx * 8);
        float4 w0 = swp[0], w1 = swp[1];
        unsigned short* Wb = W + (size_t)o * KDIM + f;
        Wb[0 * 1024] = f2bf(w0.x * scale);
        Wb[1 * 1024] = f2bf(w0.y * scale);
        Wb[2 * 1024] = f2bf(w0.z * scale);
        Wb[3 * 1024] = f2bf(w0.w * scale);
        Wb[4 * 1024] = f2bf(w1.x * scale);
        Wb[5 * 1024] = f2bf(w1.y * scale);
        Wb[6 * 1024] = f2bf(w1.z * scale);
        Wb[7 * 1024] = f2bf(w1.w * scale);
        Wb[8 * 1024] = f2bf(bw[idx]);
    }
}

// ---------------------------------------------------------------------------
// Kernel 2: m201-style 8-phase GEMM, K-split x2.
// LDS (u16): buf0.A 0 | buf0.B 16384 | buf1.A 32768 | buf1.B 49152 (128 KiB).
// Tile layout: rows linear, 8x16B chunks/row, chunk ^= (row&7) (r2-measured 0
// conflicts at BK=64). Stage = half-tile (128 rows) = 2 global_load_lds/thread.
// Iteration t: tiles T=2t (buf0), T+1 (buf1). Stages (1 half/phase):
//   ph0:(T+1)Ah0->b1  ph1:(T+1)Ah1->b1  ph2:(T+2)Bh0->b0  ph3:(T+2)Bh1->b0
//   ph4:(T+2)Ah0->b0  ph5:(T+2)Ah1->b0  ph6:(T+3)Bh0->b1  ph7:(T+3)Bh1->b1
// Every target slot is >=1 barrier past its last read. Counted waits:
//   ph3-end vmcnt(4): retires (T+1) fully (leaves (T+2)Bh0,Bh1 in flight)
//   ph7-end vmcnt(4): retires (T+2) fully (leaves (T+3)Bh0,Bh1 in flight)
// Never 0 until the last iteration.
// ---------------------------------------------------------------------------
#define STG_A(h, tt, bsel) do { \
    __builtin_amdgcn_global_load_lds((glb_u16*)(pa0 + (size_t)(h) * 128 * KDIM + (size_t)(tt) * 64), \
        (lds_u16*)lds + (bsel) * 32768 + (h) * 8192 + da0, 16, 0, 0); \
    __builtin_amdgcn_global_load_lds((glb_u16*)(pa1 + (size_t)(h) * 128 * KDIM + (size_t)(tt) * 64), \
        (lds_u16*)lds + (bsel) * 32768 + (h) * 8192 + da1, 16, 0, 0); \
} while (0)

#define STG_B(h, tt, bsel) do { \
    __builtin_amdgcn_global_load_lds((glb_u16*)(pb0 + (size_t)(h) * 128 * KDIM + (size_t)(tt) * 64), \
        (lds_u16*)lds + (bsel) * 32768 + 16384 + (h) * 8192 + da0, 16, 0, 0); \
    __builtin_amdgcn_global_load_lds((glb_u16*)(pb1 + (size_t)(h) * 128 * KDIM + (size_t)(tt) * 64), \
        (lds_u16*)lds + (bsel) * 32768 + 16384 + (h) * 8192 + da1, 16, 0, 0); \
} while (0)

#define RD(off) (*(const bf16x8*)&lds[off])

// mi group (0-3 at moff=0, 4-7 at moff=4096) from A region at `ab`
#define RDA4(ab, moff) do { \
    _Pragma("unroll") for (int i = 0; i < 4; ++i) { \
        a[i][0] = RD((ab) + ra + (moff) + i * 1024 + ko0); \
        a[i][1] = RD((ab) + ra + (moff) + i * 1024 + ko1); } \
} while (0)

// ni pair NB,NB+1 from B region at `bb`
#define RDB2(bb, NB) do { \
    _Pragma("unroll") for (int jq = 0; jq < 2; ++jq) { \
        b[(NB) + jq][0] = RD((bb) + rb + ((NB) + jq) * 1024 + ko0); \
        b[(NB) + jq][1] = RD((bb) + rb + ((NB) + jq) * 1024 + ko1); } \
} while (0)

#define MM16(MB, NB) do { \
    _Pragma("unroll") for (int i = 0; i < 4; ++i) \
        _Pragma("unroll") for (int jq = 0; jq < 2; ++jq) { \
            acc[(MB) + i][(NB) + jq] = __builtin_amdgcn_mfma_f32_16x16x32_bf16( \
                a[i][0], b[(NB) + jq][0], acc[(MB) + i][(NB) + jq], 0, 0, 0); \
            acc[(MB) + i][(NB) + jq] = __builtin_amdgcn_mfma_f32_16x16x32_bf16( \
                a[i][1], b[(NB) + jq][1], acc[(MB) + i][(NB) + jq], 0, 0, 0); } \
} while (0)

#define BAR()  __builtin_amdgcn_s_barrier()
#define LGK0() asm volatile("s_waitcnt lgkmcnt(0)" ::: "memory")
#define PRIO(n) __builtin_amdgcn_s_setprio(n)

__global__ __launch_bounds__(512, 2) void gemm_8p(
    const unsigned short* __restrict__ Ap,
    const unsigned short* __restrict__ Wp,
    float* __restrict__ C, float* __restrict__ P, int mode) {
    __shared__ unsigned short lds[65536];                // 128 KiB

    const int tid  = threadIdx.x;
    const int wave = tid >> 6;
    const int lane = tid & 63;
    const int lm16 = lane & 15;
    const int lhi  = lane >> 4;
    const int ko0  = ((lhi ^ (lm16 & 7)) << 3);          // kk=0 chunk (swizzled)
    const int ko1  = ko0 ^ 32;                           // kk=1 (chunk ^ 4)

    const int bid  = blockIdx.x;
    const int mg   = bid & 3;
    const int kb   = (bid >> 2) & 1;
    const int j    = bid >> 3;
    const int m0   = (mg * 8 + (j >> 2)) * BM;
    const int n0   = (j & 3) * BN;
    const int kbase = kb * KHALF;

    const int wr = wave >> 2;                            // 0..1 (M)
    const int wc = wave & 3;                             // 0..3 (N)
    const int ra = ((wr << 7) + lm16) << 6;              // A row base (u16)
    const int rb = ((wc << 6) + lm16) << 6;              // B row base (u16)

    f32x4 acc[8][4];
#pragma unroll
    for (int i = 0; i < 8; ++i)
#pragma unroll
        for (int jn = 0; jn < 4; ++jn) acc[i][jn] = (f32x4)(0.0f);

    // staging pointers: thread handles chunks ci0 (rows 0-63) and ci1 (64-127)
    // of each 128-row half; source chunk pre-swizzled: c ^ (row&7).
    const int ci0 = tid, ci1 = 512 + tid;
    const int da0 = ci0 << 3, da1 = ci1 << 3;
    const unsigned short* pa0 = Ap + (size_t)(m0 + (ci0 >> 3)) * KDIM + kbase + (((ci0 & 7) ^ ((ci0 >> 3) & 7)) << 3);
    const unsigned short* pa1 = Ap + (size_t)(m0 + (ci1 >> 3)) * KDIM + kbase + (((ci1 & 7) ^ ((ci1 >> 3) & 7)) << 3);
    const unsigned short* pb0 = Wp + (size_t)(n0 + (ci0 >> 3)) * KDIM + kbase + (((ci0 & 7) ^ ((ci0 >> 3) & 7)) << 3);
    const unsigned short* pb1 = Wp + (size_t)(n0 + (ci1 >> 3)) * KDIM + kbase + (((ci1 & 7) ^ ((ci1 >> 3) & 7)) << 3);

    bf16x8 a[4][2], b[4][2];

    // prologue: T0 fully (B h0,h1 then A h0,h1) -> buf0; T1 B h0,h1 -> buf1.
    STG_B(0, 0, 0); STG_B(1, 0, 0); STG_A(0, 0, 0); STG_A(1, 0, 0);
    STG_B(0, 1, 1); STG_B(1, 1, 1);
    asm volatile("s_waitcnt vmcnt(4)" ::: "memory");     // T0 landed; T1.B in flight
    BAR();

#pragma unroll 1
    for (int t = 0; t < NT2; ++t) {
        const int T = 2 * t;
        const bool pf = (t < NT2 - 1);

        // ---- ph0: reads a(mi0-3), b(ni0-1) of buf0; stage (T+1).Ah0 -> buf1
        RDA4(0, 0); RDB2(16384, 0);
        STG_A(0, T + 1, 1);
        BAR(); LGK0(); PRIO(1); MM16(0, 0); PRIO(0); BAR();

        // ---- ph1: reads b(ni2-3); stage (T+1).Ah1 -> buf1
        RDB2(16384, 2);
        STG_A(1, T + 1, 1);
        BAR(); LGK0(); PRIO(1); MM16(0, 2); PRIO(0); BAR();

        // ---- ph2: reads a(mi4-7); stage (T+2).Bh0 -> buf0 (B free since ph2)
        RDA4(0, 4096);
        if (pf) STG_B(0, T + 2, 0);
        BAR(); LGK0(); PRIO(1); MM16(4, 2); PRIO(0); BAR();

        // ---- ph3: no reads; stage (T+2).Bh1 -> buf0; counted wait for (T+1)
        if (pf) STG_B(1, T + 2, 0);
        BAR(); PRIO(1); MM16(4, 0); PRIO(0);
        if (pf) asm volatile("s_waitcnt vmcnt(4)" ::: "memory");
        else    asm volatile("s_waitcnt vmcnt(0)" ::: "memory");
        BAR();

        // ---- ph4: tile T+1 (buf1): reads a(mi0-3), b(ni0-1); stage (T+2).Ah0 -> buf0
        RDA4(32768, 0); RDB2(49152, 0);
        if (pf) STG_A(0, T + 2, 0);
        BAR(); LGK0(); PRIO(1); MM16(0, 0); PRIO(0); BAR();

        // ---- ph5: reads b(ni2-3); stage (T+2).Ah1 -> buf0
        RDB2(49152, 2);
        if (pf) STG_A(1, T + 2, 0);
        BAR(); LGK0(); PRIO(1); MM16(0, 2); PRIO(0); BAR();

        // ---- ph6: reads a(mi4-7); stage (T+3).Bh0 -> buf1 (B free since ph6)
        RDA4(32768, 4096);
        if (pf) STG_B(0, T + 3, 1);
        BAR(); LGK0(); PRIO(1); MM16(4, 2); PRIO(0); BAR();

        // ---- ph7: no reads; stage (T+3).Bh1 -> buf1; counted wait for (T+2)
        if (pf) STG_B(1, T + 3, 1);
        BAR(); PRIO(1); MM16(4, 0); PRIO(0);
        if (pf) asm volatile("s_waitcnt vmcnt(4)" ::: "memory");
        else    asm volatile("s_waitcnt vmcnt(0)" ::: "memory");
        BAR();
    }

    // epilogue: C/D layout col = lane&15, row = (lane>>4)*4 + r
    const int orow = m0 + wr * 128 + (lhi << 2);
    const int ocol = n0 + wc * 64 + lm16;
    if (mode) {
#pragma unroll
        for (int mi = 0; mi < 8; ++mi)
#pragma unroll
            for (int ni = 0; ni < 4; ++ni)
#pragma unroll
                for (int r = 0; r < 4; ++r)
                    atomicAdd(&C[(size_t)(orow + mi * 16 + r) * OUT_F + (ocol + ni * 16)], acc[mi][ni][r]);
    } else {
        float* dst = kb ? P : C;
#pragma unroll
        for (int mi = 0; mi < 8; ++mi)
#pragma unroll
            for (int ni = 0; ni < 4; ++ni)
#pragma unroll
                for (int r = 0; r < 4; ++r)
                    dst[(size_t)(orow + mi * 16 + r) * OUT_F + (ocol + ni * 16)] = acc[mi][ni][r];
    }
}

// ---------------------------------------------------------------------------
// Kernel 3: C += P (K-split reduction), float4.
// ---------------------------------------------------------------------------
__global__ void add_kernel(float* __restrict__ C, const float* __restrict__ P) {
    int i = blockIdx.x * blockDim.x + threadIdx.x;
    if (i >= BATCH * OUT_F / 4) return;
    f32x4* c4 = (f32x4*)C;
    const f32x4* p4 = (const f32x4*)P;
    c4[i] = c4[i] + p4[i];
}

// ---------------------------------------------------------------------------
extern "C" void kernel_launch(void* const* d_in, const int* in_sizes, int n_in,
                              void* d_out, int out_size, void* d_ws, size_t ws_size,
                              hipStream_t stream) {
    const float* x             = (const float*)d_in[0];
    const float* base_weight   = (const float*)d_in[1];
    const float* spline_weight = (const float*)d_in[2];
    const float* spline_scaler = (const float*)d_in[3];
    float* out = (float*)d_out;

    const size_t wbytes = (size_t)OUT_F * KDIM * 2;      // 18.9 MB
    const size_t abytes = (size_t)BATCH * KDIM * 2;      // 151 MB
    const size_t pbytes = (size_t)BATCH * OUT_F * 4;     // 33.5 MB
    unsigned short* Wc   = (unsigned short*)d_ws;
    unsigned short* Abuf = (unsigned short*)((char*)d_ws + wbytes);
    float*          P    = (float*)((char*)d_ws + wbytes + abytes);

    const int mode = (ws_size >= wbytes + abytes + pbytes) ? 0 : 1;
    if (mode == 1)
        (void)hipMemsetAsync(d_out, 0, pbytes, stream);  // atomic fallback needs zeroed C

    prep_kernel<<<8192, 256, 0, stream>>>(x, base_weight, spline_weight,
                                          spline_scaler, Abuf, Wc);

    gemm_8p<<<256, 512, 0, stream>>>(Abuf, Wc, out, P, mode);

    if (mode == 0)
        add_kernel<<<(BATCH * OUT_F / 4 + 255) / 256, 256, 0, stream>>>(out, P);
}